// Round 2
// baseline (386.492 us; speedup 1.0000x reference)
//
#include <hip/hip_runtime.h>
#include <hip/hip_bf16.h>

#define NN 4096
#define IN_DIM 512
#define NH 8
#define DD 64
#define HD 512    // NH*DD
#define LOG2E 1.4426950408889634f
#define CAST_WGS 2304   // (524288+65536)/256 exactly
#define SCAN_WGS 1024
#define FLASH_WGS 256   // NN/16

// Workspace: d1t 4MB + Ab 4MB + Wb 0.5MB + srcT/trgT 0.25MB + bm 2MB = 10.75 MB
// (R3 lesson: stay well under ~12 MB.)

typedef __attribute__((ext_vector_type(8))) short short8;
typedef __attribute__((ext_vector_type(4))) float f32x4;

static __device__ __forceinline__ unsigned short f2bf(float x) {
    __hip_bfloat16 h = __float2bfloat16(x);
    return *reinterpret_cast<unsigned short*>(&h);
}

// ---------------- K0: bf16 cast of data/W + conn edge-bitmask scan -----------
// Cast blocks [0, CAST_WGS); scan blocks [CAST_WGS, CAST_WGS+SCAN_WGS).
// Both paths are pure streaming (cast 13.5MB, scan 64MB read / 2MB write) —
// pairing them keeps the 64MB conn stream away from the GEMM's L2 working set
// (round-1 lesson: scan fused into the GEMM gave zero net overlap).
__global__ __launch_bounds__(256) void k_cast_scan(const float* __restrict__ inA,
                                                   unsigned short* __restrict__ outA,
                                                   int n4A,
                                                   const float* __restrict__ inB,
                                                   unsigned short* __restrict__ outB,
                                                   int n4B,
                                                   const float* __restrict__ conn,
                                                   unsigned long long* __restrict__ bm) {
    if (blockIdx.x >= CAST_WGS) {
        // ---- conn scan: one row per wave, u64 word per 64 columns ----
        const int lane = threadIdx.x & 63;
        const int w = threadIdx.x >> 6;
        const int row = (blockIdx.x - CAST_WGS) * 4 + w;
        const float* crow = conn + (size_t)row * NN;
        unsigned long long keep = 0;
#pragma unroll 8
        for (int t = 0; t < 64; t++) {
            float c = crow[t * 64 + lane];                 // 256B coalesced
            unsigned long long m = __ballot(c == 0.0f);    // kept edge == 0.0f
            if (lane == t) keep = m;
        }
        bm[(size_t)row * 64 + lane] = keep;                // 512B coalesced
        return;
    }
    int t = blockIdx.x * 256 + threadIdx.x;
    const float* in;
    unsigned short* out;
    if (t < n4A) {
        in = inA; out = outA;
    } else {
        t -= n4A;
        if (t >= n4B) return;
        in = inB; out = outB;
    }
    float4 v = ((const float4*)in)[t];
    ushort4 o;
    o.x = f2bf(v.x); o.y = f2bf(v.y); o.z = f2bf(v.z); o.w = f2bf(v.w);
    ((ushort4*)out)[t] = o;
}

// ---------------- K1: GEMM (bf16 MFMA) + fused src/trg projection ------------
// 64n x 64m per WG; m-tile == head h = blockIdx.x. Fragments straight from
// global (k-major). C/D: col=lane&15, row=(lane>>4)*4+reg (m89-verified).
// Epilogue writes the TRANSPOSED value matrix d1t[m][n] (bf16, packed ushort4
// stores) — that is exactly the MFMA B-fragment layout the flash kernel needs
// — plus srcT/trgT[h][n] pre-scaled by LOG2E (exp -> bare v_exp_f32 later;
// leaky(c*x)=c*leaky(x) for c>0 so the scale commutes through LeakyReLU).
__global__ __launch_bounds__(256) void k_gemm_fused(const unsigned short* __restrict__ Ab,
                                                    const unsigned short* __restrict__ Wb,
                                                    const float* __restrict__ bias,
                                                    const float* __restrict__ sp,
                                                    const float* __restrict__ tp,
                                                    unsigned short* __restrict__ d1t,
                                                    float* __restrict__ srcT,
                                                    float* __restrict__ trgT) {
    const int lane = threadIdx.x & 63;
    const int w = threadIdx.x >> 6;
    const int col = lane & 15;
    const int quad = lane >> 4;
    const int koff = quad * 8;
    const int h = blockIdx.x;
    const int m0 = h * 64;
    const int n0 = blockIdx.y * 64;

    const short8* ap  = (const short8*)(Ab + (size_t)(n0 + w * 16 + col) * IN_DIM + koff);
    const short8* bp0 = (const short8*)(Wb + (size_t)(m0 +  0 + col) * IN_DIM + koff);
    const short8* bp1 = (const short8*)(Wb + (size_t)(m0 + 16 + col) * IN_DIM + koff);
    const short8* bp2 = (const short8*)(Wb + (size_t)(m0 + 32 + col) * IN_DIM + koff);
    const short8* bp3 = (const short8*)(Wb + (size_t)(m0 + 48 + col) * IN_DIM + koff);

    f32x4 acc0 = {0.f, 0.f, 0.f, 0.f}, acc1 = acc0, acc2 = acc0, acc3 = acc0;

#pragma unroll 4
    for (int ks = 0; ks < 16; ks++) {
        short8 a  = ap[ks * 4];
        short8 b0 = bp0[ks * 4];
        short8 b1 = bp1[ks * 4];
        short8 b2 = bp2[ks * 4];
        short8 b3 = bp3[ks * 4];
        acc0 = __builtin_amdgcn_mfma_f32_16x16x32_bf16(a, b0, acc0, 0, 0, 0);
        acc1 = __builtin_amdgcn_mfma_f32_16x16x32_bf16(a, b1, acc1, 0, 0, 0);
        acc2 = __builtin_amdgcn_mfma_f32_16x16x32_bf16(a, b2, acc2, 0, 0, 0);
        acc3 = __builtin_amdgcn_mfma_f32_16x16x32_bf16(a, b3, acc3, 0, 0, 0);
    }

    const int rbase = n0 + w * 16 + quad * 4;
    f32x4 accs[4] = {acc0, acc1, acc2, acc3};
    float ps[4] = {0.f, 0.f, 0.f, 0.f};
    float pt[4] = {0.f, 0.f, 0.f, 0.f};
#pragma unroll
    for (int mt = 0; mt < 4; mt++) {
        const int m = m0 + mt * 16 + col;
        const float bv  = bias[m];
        const float spv = sp[m];
        const float tpv = tp[m];
        ushort4 pack;
        unsigned short* pk = (unsigned short*)&pack;
#pragma unroll
        for (int r = 0; r < 4; r++) {
            float v = accs[mt][r] + bv;
            pk[r] = f2bf(v);
            ps[r] += v * spv;
            pt[r] += v * tpv;
        }
        *(ushort4*)(d1t + (size_t)m * NN + rbase) = pack;   // d1t[m][rbase..+3]
    }
#pragma unroll
    for (int off = 1; off <= 8; off <<= 1) {
#pragma unroll
        for (int r = 0; r < 4; r++) {
            ps[r] += __shfl_xor(ps[r], off, 64);
            pt[r] += __shfl_xor(pt[r], off, 64);
        }
    }
    if (col < 4)
        srcT[(size_t)h * NN + rbase + col] = ps[col] * LOG2E;
    else if (col < 8)
        trgT[(size_t)h * NN + rbase + col - 4] = pt[col - 4] * LOG2E;
}

// ---------------- K2: dense flash attention over the bitmask -----------------
// 256 blocks x 256 thr; block = i-tile of 16 rows; wave w handles heads 2w,2w+1.
// Per j-tile (32 cols): build P = exp2(leaky(s+t) + (bit?0:-200)) directly in
// MFMA A-fragment layout (lane row = l&15, k = (l>>4)*8+r), pack to bf16, and
// accumulate out += P x Vt with 8 mfma_16x16x32. Non-edges give p == 0.0f
// exactly (2^-196 underflows), so semantics match the sparse version. The
// denominator rides along as a lane-local f32 sum (no extra pass). No LDS, no
// barriers; all operands are contiguous L2/L3-resident loads (bm 2MB, Vt 4MB,
// trgT 128KB). conn (64MB) is never touched here.
__global__ __launch_bounds__(256) void k_flash(const unsigned* __restrict__ bm32,
                                               const float* __restrict__ srcT,
                                               const float* __restrict__ trgT,
                                               const unsigned short* __restrict__ d1t,
                                               float* __restrict__ out) {
    const int lane = threadIdx.x & 63;
    const int w = threadIdx.x >> 6;
    const int col = lane & 15;
    const int kq = lane >> 4;
    const int i0 = blockIdx.x * 16;
    const int h0 = w * 2;
    const int m = i0 + col;                 // the P-row this lane builds
    const int sh0 = kq * 8;

    const float s0 = srcT[(size_t)h0 * NN + m];
    const float s1 = srcT[(size_t)(h0 + 1) * NN + m];
    const unsigned* bp = bm32 + (size_t)m * 128;          // one u32 per j-tile
    const float* tp0 = trgT + (size_t)h0 * NN + sh0;
    const float* tp1 = tp0 + NN;
    const short8* vp[2][4];
#pragma unroll
    for (int hh = 0; hh < 2; hh++)
#pragma unroll
        for (int dt = 0; dt < 4; dt++)
            vp[hh][dt] = (const short8*)(d1t +
                (size_t)((h0 + hh) * 64 + dt * 16 + col) * NN + sh0);

    f32x4 acc[2][4];
#pragma unroll
    for (int hh = 0; hh < 2; hh++)
#pragma unroll
        for (int dt = 0; dt < 4; dt++)
            acc[hh][dt] = (f32x4){0.f, 0.f, 0.f, 0.f};
    float ds0 = 0.f, ds1 = 0.f;

#pragma unroll 2
    for (int jt = 0; jt < 128; jt++) {
        const unsigned bw = bp[jt];
        const float4 ta = *(const float4*)(tp0 + jt * 32);
        const float4 tb = *(const float4*)(tp0 + jt * 32 + 4);
        const float4 tc = *(const float4*)(tp1 + jt * 32);
        const float4 td = *(const float4*)(tp1 + jt * 32 + 4);
        short8 v00 = vp[0][0][jt * 4];
        short8 v01 = vp[0][1][jt * 4];
        short8 v02 = vp[0][2][jt * 4];
        short8 v03 = vp[0][3][jt * 4];
        short8 v10 = vp[1][0][jt * 4];
        short8 v11 = vp[1][1][jt * 4];
        short8 v12 = vp[1][2][jt * 4];
        short8 v13 = vp[1][3][jt * 4];

        const float t0a[8] = {ta.x, ta.y, ta.z, ta.w, tb.x, tb.y, tb.z, tb.w};
        const float t1a[8] = {tc.x, tc.y, tc.z, tc.w, td.x, td.y, td.z, td.w};
        float p0[8], p1[8];
#pragma unroll
        for (int r = 0; r < 8; r++) {
            unsigned b = (bw >> (sh0 + r)) & 1u;
            // b==1 -> +0.0f ; b==0 -> -200.0f (exp2 -> exact 0.0f)
            float msk = __uint_as_float((b - 1u) & 0xC3480000u);
            float e0 = s0 + t0a[r];
            e0 = fmaxf(e0, 0.01f * e0) + msk;          // LeakyReLU then mask
            p0[r] = __builtin_amdgcn_exp2f(e0);
            ds0 += p0[r];
            float e1 = s1 + t1a[r];
            e1 = fmaxf(e1, 0.01f * e1) + msk;
            p1[r] = __builtin_amdgcn_exp2f(e1);
            ds1 += p1[r];
        }
        short8 pa0, pa1;
#pragma unroll
        for (int r = 0; r < 8; r++) {
            pa0[r] = (short)f2bf(p0[r]);
            pa1[r] = (short)f2bf(p1[r]);
        }
        acc[0][0] = __builtin_amdgcn_mfma_f32_16x16x32_bf16(pa0, v00, acc[0][0], 0, 0, 0);
        acc[0][1] = __builtin_amdgcn_mfma_f32_16x16x32_bf16(pa0, v01, acc[0][1], 0, 0, 0);
        acc[0][2] = __builtin_amdgcn_mfma_f32_16x16x32_bf16(pa0, v02, acc[0][2], 0, 0, 0);
        acc[0][3] = __builtin_amdgcn_mfma_f32_16x16x32_bf16(pa0, v03, acc[0][3], 0, 0, 0);
        acc[1][0] = __builtin_amdgcn_mfma_f32_16x16x32_bf16(pa1, v10, acc[1][0], 0, 0, 0);
        acc[1][1] = __builtin_amdgcn_mfma_f32_16x16x32_bf16(pa1, v11, acc[1][1], 0, 0, 0);
        acc[1][2] = __builtin_amdgcn_mfma_f32_16x16x32_bf16(pa1, v12, acc[1][2], 0, 0, 0);
        acc[1][3] = __builtin_amdgcn_mfma_f32_16x16x32_bf16(pa1, v13, acc[1][3], 0, 0, 0);
    }

    // denominators: lane-local sums -> reduce across the 4 k-quads
    ds0 += __shfl_xor(ds0, 16, 64);
    ds0 += __shfl_xor(ds0, 32, 64);
    ds1 += __shfl_xor(ds1, 16, 64);
    ds1 += __shfl_xor(ds1, 32, 64);

    // C layout: row = kq*4 + r (i-row), col = l&15 (d). Row-sum lives on lane
    // (kq*4+r) (its col == that row index) -> shfl it over, normalize, store.
#pragma unroll
    for (int r = 0; r < 4; r++) {
        const int row = i0 + kq * 4 + r;
        float d0 = __shfl(ds0, kq * 4 + r, 64);
        float d1 = __shfl(ds1, kq * 4 + r, 64);
        float inv0 = (d0 > 0.f) ? (1.f / d0) : 0.f;
        float inv1 = (d1 > 0.f) ? (1.f / d1) : 0.f;
        float* op = out + (size_t)row * HD + h0 * 64;
#pragma unroll
        for (int dt = 0; dt < 4; dt++) {
            op[dt * 16 + col]      = acc[0][dt][r] * inv0;
            op[64 + dt * 16 + col] = acc[1][dt][r] * inv1;
        }
    }
}

extern "C" void kernel_launch(void* const* d_in, const int* in_sizes, int n_in,
                              void* d_out, int out_size, void* d_ws, size_t ws_size,
                              hipStream_t stream) {
    const float* data = (const float*)d_in[0];   // (4096, 512)
    const float* conn = (const float*)d_in[1];   // (4096, 4096)
    const float* W    = (const float*)d_in[2];   // (512, 512)
    const float* bias = (const float*)d_in[3];   // (512,)
    const float* sp   = (const float*)d_in[4];   // (1, 8, 64)
    const float* tp   = (const float*)d_in[5];   // (1, 8, 64)
    float* out = (float*)d_out;                  // (4096, 512) fp32

    unsigned short* d1t = (unsigned short*)d_ws;              // 512x4096 bf16 (4 MB)
    unsigned short* Ab  = d1t + (size_t)HD * NN;              // 2M bf16 (4 MB)
    unsigned short* Wb  = Ab + (size_t)NN * IN_DIM;           // 256K bf16 (512 KB)
    float* srcT = (float*)(Wb + (size_t)HD * IN_DIM);         // 8x4096 f32 (128 KB)
    float* trgT = srcT + NH * NN;                             // 128 KB
    unsigned long long* bm = (unsigned long long*)(trgT + NH * NN); // 2 MB
    // total ~10.75 MB

    const int n4A = NN * IN_DIM / 4;   // 524288
    const int n4B = HD * IN_DIM / 4;   // 65536
    k_cast_scan<<<dim3(CAST_WGS + SCAN_WGS), 256, 0, stream>>>(data, Ab, n4A, W, Wb, n4B,
                                                               conn, bm);
    k_gemm_fused<<<dim3(NH, NN / 64), 256, 0, stream>>>(Ab, Wb, bias, sp, tp,
                                                        d1t, srcT, trgT);
    k_flash<<<dim3(FLASH_WGS), 256, 0, stream>>>((const unsigned*)bm, srcT, trgT, d1t, out);
}

// Round 3
// 223.455 us; speedup vs baseline: 1.7296x; 1.7296x over previous
//
#include <hip/hip_runtime.h>
#include <hip/hip_bf16.h>

#define NN 4096
#define IN_DIM 512
#define NH 8
#define DD 64
#define HD 512    // NH*DD
#define LOG2E 1.4426950408889634f
#define CAST_WGS 2304   // (524288+65536)/256 exactly
#define SCAN_WGS 1024

// Workspace: d1t 4MB + Ab 4MB + Wb 0.5MB + srcT/trgT 0.25MB + bm 2MB = 10.75 MB
// (R3 lesson: stay well under ~12 MB.)

typedef __attribute__((ext_vector_type(8))) short short8;
typedef __attribute__((ext_vector_type(4))) float f32x4;

static __device__ __forceinline__ unsigned short f2bf(float x) {
    __hip_bfloat16 h = __float2bfloat16(x);
    return *reinterpret_cast<unsigned short*>(&h);
}

// ---------------- K0: bf16 cast of data/W + conn edge-bitmask scan -----------
// (unchanged from R2 — kept stable to isolate the flash rewrite)
__global__ __launch_bounds__(256) void k_cast_scan(const float* __restrict__ inA,
                                                   unsigned short* __restrict__ outA,
                                                   int n4A,
                                                   const float* __restrict__ inB,
                                                   unsigned short* __restrict__ outB,
                                                   int n4B,
                                                   const float* __restrict__ conn,
                                                   unsigned long long* __restrict__ bm) {
    if (blockIdx.x >= CAST_WGS) {
        const int lane = threadIdx.x & 63;
        const int w = threadIdx.x >> 6;
        const int row = (blockIdx.x - CAST_WGS) * 4 + w;
        const float* crow = conn + (size_t)row * NN;
        unsigned long long keep = 0;
#pragma unroll 8
        for (int t = 0; t < 64; t++) {
            float c = crow[t * 64 + lane];                 // 256B coalesced
            unsigned long long m = __ballot(c == 0.0f);    // kept edge == 0.0f
            if (lane == t) keep = m;
        }
        bm[(size_t)row * 64 + lane] = keep;                // 512B coalesced
        return;
    }
    int t = blockIdx.x * 256 + threadIdx.x;
    const float* in;
    unsigned short* out;
    if (t < n4A) {
        in = inA; out = outA;
    } else {
        t -= n4A;
        if (t >= n4B) return;
        in = inB; out = outB;
    }
    float4 v = ((const float4*)in)[t];
    ushort4 o;
    o.x = f2bf(v.x); o.y = f2bf(v.y); o.z = f2bf(v.z); o.w = f2bf(v.w);
    ((ushort4*)out)[t] = o;
}

// ---------------- K1: GEMM (bf16 MFMA) + fused src/trg projection ------------
// (unchanged from R2 — writes transposed d1t[m][n] + srcT/trgT pre-scaled by
// LOG2E so the flash kernel uses a bare v_exp_f32.)
__global__ __launch_bounds__(256) void k_gemm_fused(const unsigned short* __restrict__ Ab,
                                                    const unsigned short* __restrict__ Wb,
                                                    const float* __restrict__ bias,
                                                    const float* __restrict__ sp,
                                                    const float* __restrict__ tp,
                                                    unsigned short* __restrict__ d1t,
                                                    float* __restrict__ srcT,
                                                    float* __restrict__ trgT) {
    const int lane = threadIdx.x & 63;
    const int w = threadIdx.x >> 6;
    const int col = lane & 15;
    const int quad = lane >> 4;
    const int koff = quad * 8;
    const int h = blockIdx.x;
    const int m0 = h * 64;
    const int n0 = blockIdx.y * 64;

    const short8* ap  = (const short8*)(Ab + (size_t)(n0 + w * 16 + col) * IN_DIM + koff);
    const short8* bp0 = (const short8*)(Wb + (size_t)(m0 +  0 + col) * IN_DIM + koff);
    const short8* bp1 = (const short8*)(Wb + (size_t)(m0 + 16 + col) * IN_DIM + koff);
    const short8* bp2 = (const short8*)(Wb + (size_t)(m0 + 32 + col) * IN_DIM + koff);
    const short8* bp3 = (const short8*)(Wb + (size_t)(m0 + 48 + col) * IN_DIM + koff);

    f32x4 acc0 = {0.f, 0.f, 0.f, 0.f}, acc1 = acc0, acc2 = acc0, acc3 = acc0;

#pragma unroll 4
    for (int ks = 0; ks < 16; ks++) {
        short8 a  = ap[ks * 4];
        short8 b0 = bp0[ks * 4];
        short8 b1 = bp1[ks * 4];
        short8 b2 = bp2[ks * 4];
        short8 b3 = bp3[ks * 4];
        acc0 = __builtin_amdgcn_mfma_f32_16x16x32_bf16(a, b0, acc0, 0, 0, 0);
        acc1 = __builtin_amdgcn_mfma_f32_16x16x32_bf16(a, b1, acc1, 0, 0, 0);
        acc2 = __builtin_amdgcn_mfma_f32_16x16x32_bf16(a, b2, acc2, 0, 0, 0);
        acc3 = __builtin_amdgcn_mfma_f32_16x16x32_bf16(a, b3, acc3, 0, 0, 0);
    }

    const int rbase = n0 + w * 16 + quad * 4;
    f32x4 accs[4] = {acc0, acc1, acc2, acc3};
    float ps[4] = {0.f, 0.f, 0.f, 0.f};
    float pt[4] = {0.f, 0.f, 0.f, 0.f};
#pragma unroll
    for (int mt = 0; mt < 4; mt++) {
        const int m = m0 + mt * 16 + col;
        const float bv  = bias[m];
        const float spv = sp[m];
        const float tpv = tp[m];
        ushort4 pack;
        unsigned short* pk = (unsigned short*)&pack;
#pragma unroll
        for (int r = 0; r < 4; r++) {
            float v = accs[mt][r] + bv;
            pk[r] = f2bf(v);
            ps[r] += v * spv;
            pt[r] += v * tpv;
        }
        *(ushort4*)(d1t + (size_t)m * NN + rbase) = pack;   // d1t[m][rbase..+3]
    }
#pragma unroll
    for (int off = 1; off <= 8; off <<= 1) {
#pragma unroll
        for (int r = 0; r < 4; r++) {
            ps[r] += __shfl_xor(ps[r], off, 64);
            pt[r] += __shfl_xor(pt[r], off, 64);
        }
    }
    if (col < 4)
        srcT[(size_t)h * NN + rbase + col] = ps[col] * LOG2E;
    else if (col < 8)
        trgT[(size_t)h * NN + rbase + col - 4] = pt[col - 4] * LOG2E;
}

// ---------------- K2: dense flash attention, LDS-tiled (v2) ------------------
// R2 post-mortem: v1 had 1 wave/SIMD, zero inter-wave sharing -> 1 GB L2
// traffic, 4900 cy/iter of exposed latency (259 us, VALUBusy 13%).
// v2: block = 64 i-rows x 1 head (grid 64x8 = 512 blocks -> 2 waves/SIMD);
// all 4 waves share one 4KB Vt tile staged in LDS (double-buffered, reg-staged
// with the T14 issue-early/write-late split, ONE barrier per jt). L2 traffic
// drops ~4x to ~280MB. ds_read_b128 B-frags use an XOR row-swizzle
// (slot ^= row&3) -> ~2-way banks (free) instead of 16-way.
// Per jt per wave: 4 ds_read + 8 masked exp2 + 4 MFMA. Mask is a post-exp
// multiply by (float)bit -> p==0.0 exactly for non-edges (same semantics).
__global__ __launch_bounds__(256) void k_flash(const unsigned* __restrict__ bm32,
                                               const float* __restrict__ srcT,
                                               const float* __restrict__ trgT,
                                               const unsigned short* __restrict__ d1t,
                                               float* __restrict__ out) {
    __shared__ uint4 vt[2][256];            // 2 x 4KB Vt tile (64 rows x 64B)
    char* vb = (char*)vt;

    const int t = threadIdx.x;
    const int lane = t & 63;
    const int w = t >> 6;
    const int col = lane & 15;
    const int kq = lane >> 4;
    const int i0 = blockIdx.x * 64;
    const int h = blockIdx.y;
    const int m = i0 + w * 16 + col;        // this lane's P row

    // staging: thread t covers Vt row (t>>2) of this head, 16B slot (t&3)
    const int srow = t >> 2;
    const int sslot = t & 3;
    const uint4* gsrc = (const uint4*)(d1t + (size_t)(h * 64 + srow) * NN) + sslot;
    const unsigned wbyte = (unsigned)(srow * 64 + ((sslot ^ (srow & 3)) << 4));
    // read side: lane reads LDS row (dt*16+col), global slot kq -> swizzled
    const unsigned rb = (unsigned)(col * 64 + ((kq ^ (col & 3)) << 4));

    const float s = srcT[(size_t)h * NN + m];
    const unsigned* bp = bm32 + (size_t)m * 128;          // one u32 per j-tile
    const float* tpp = trgT + (size_t)h * NN + kq * 8;

    f32x4 acc0 = {0.f, 0.f, 0.f, 0.f}, acc1 = acc0, acc2 = acc0, acc3 = acc0;
    float ds = 0.f;

    // prologue: stage tile 0
    {
        uint4 st = gsrc[0];
        *(uint4*)(vb + wbyte) = st;
    }
    __syncthreads();

    int cur = 0;
    for (int jt = 0; jt < 128; jt++) {
        // T14 issue-early: next tile's global load flies during compute
        const int jn = (jt + 1 < 128) ? jt + 1 : 127;
        uint4 nx = gsrc[jn * 4];

        // ---- P build (8 elements: j = jt*32 + kq*8 + r) ----
        const unsigned bw = bp[jt];
        const unsigned bits = (bw >> (kq * 8)) & 0xffu;
        const float4 ta = *(const float4*)(tpp + jt * 32);
        const float4 tb2 = *(const float4*)(tpp + jt * 32 + 4);
        const float tv[8] = {ta.x, ta.y, ta.z, ta.w, tb2.x, tb2.y, tb2.z, tb2.w};
        float p[8];
#pragma unroll
        for (int r = 0; r < 8; r++) {
            float e = s + tv[r];
            e = fmaxf(e, 0.01f * e);                 // LeakyReLU (log2-scaled)
            float pv = __builtin_amdgcn_exp2f(e);
            pv *= (float)((bits >> r) & 1u);         // mask: exact 0 for non-edge
            ds += pv;
            p[r] = pv;
        }
        short8 pa;
#pragma unroll
        for (int r = 0; r < 8; r++) pa[r] = (short)f2bf(p[r]);

        // ---- B-fragments from LDS (swizzled) + 4 MFMA ----
        const char* cb = vb + cur * 4096 + rb;
        short8 v0 = *(const short8*)(cb);
        short8 v1 = *(const short8*)(cb + 1024);
        short8 v2 = *(const short8*)(cb + 2048);
        short8 v3 = *(const short8*)(cb + 3072);
        acc0 = __builtin_amdgcn_mfma_f32_16x16x32_bf16(pa, v0, acc0, 0, 0, 0);
        acc1 = __builtin_amdgcn_mfma_f32_16x16x32_bf16(pa, v1, acc1, 0, 0, 0);
        acc2 = __builtin_amdgcn_mfma_f32_16x16x32_bf16(pa, v2, acc2, 0, 0, 0);
        acc3 = __builtin_amdgcn_mfma_f32_16x16x32_bf16(pa, v3, acc3, 0, 0, 0);

        // write-late into the other buffer (readers of it finished last iter),
        // one barrier makes it visible for jt+1
        *(uint4*)(vb + (cur ^ 1) * 4096 + wbyte) = nx;
        __syncthreads();
        cur ^= 1;
    }

    // denominator: reduce lane-partials across the 4 k-quads
    ds += __shfl_xor(ds, 16, 64);
    ds += __shfl_xor(ds, 32, 64);

    // C layout: row-local = kq*4 + r, col = l&15 (d). Row-sum lives on the lane
    // whose col == that row-local index -> shfl it over, normalize, store.
    f32x4 accs[4] = {acc0, acc1, acc2, acc3};
#pragma unroll
    for (int r = 0; r < 4; r++) {
        const int row = i0 + w * 16 + kq * 4 + r;
        float dv = __shfl(ds, kq * 4 + r, 64);
        float inv = (dv > 0.f) ? (1.f / dv) : 0.f;
        float* op = out + (size_t)row * HD + h * 64;
#pragma unroll
        for (int dt = 0; dt < 4; dt++)
            op[dt * 16 + col] = accs[dt][r] * inv;
    }
}

extern "C" void kernel_launch(void* const* d_in, const int* in_sizes, int n_in,
                              void* d_out, int out_size, void* d_ws, size_t ws_size,
                              hipStream_t stream) {
    const float* data = (const float*)d_in[0];   // (4096, 512)
    const float* conn = (const float*)d_in[1];   // (4096, 4096)
    const float* W    = (const float*)d_in[2];   // (512, 512)
    const float* bias = (const float*)d_in[3];   // (512,)
    const float* sp   = (const float*)d_in[4];   // (1, 8, 64)
    const float* tp   = (const float*)d_in[5];   // (1, 8, 64)
    float* out = (float*)d_out;                  // (4096, 512) fp32

    unsigned short* d1t = (unsigned short*)d_ws;              // 512x4096 bf16 (4 MB)
    unsigned short* Ab  = d1t + (size_t)HD * NN;              // 2M bf16 (4 MB)
    unsigned short* Wb  = Ab + (size_t)NN * IN_DIM;           // 256K bf16 (512 KB)
    float* srcT = (float*)(Wb + (size_t)HD * IN_DIM);         // 8x4096 f32 (128 KB)
    float* trgT = srcT + NH * NN;                             // 128 KB
    unsigned long long* bm = (unsigned long long*)(trgT + NH * NN); // 2 MB
    // total ~10.75 MB

    const int n4A = NN * IN_DIM / 4;   // 524288
    const int n4B = HD * IN_DIM / 4;   // 65536
    k_cast_scan<<<dim3(CAST_WGS + SCAN_WGS), 256, 0, stream>>>(data, Ab, n4A, W, Wb, n4B,
                                                               conn, bm);
    k_gemm_fused<<<dim3(NH, NN / 64), 256, 0, stream>>>(Ab, Wb, bias, sp, tp,
                                                        d1t, srcT, trgT);
    k_flash<<<dim3(64, NH), 256, 0, stream>>>((const unsigned*)bm, srcT, trgT, d1t, out);
}

// Round 4
// 187.448 us; speedup vs baseline: 2.0619x; 1.1921x over previous
//
#include <hip/hip_runtime.h>
#include <hip/hip_bf16.h>

#define NN 4096
#define IN_DIM 512
#define NH 8
#define DD 64
#define HD 512    // NH*DD
#define LOG2E 1.4426950408889634f
#define CAST_WGS 2304   // (524288+65536)/256 exactly
#define SCAN_WGS 1024

// Workspace: d1t 4MB + Ab 4MB + Wb 0.5MB + srcT/trgT 0.25MB + bm 2MB = 10.75 MB
// d1t is stored in FRAGMENT ORDER: 16B chunk index [h][jt][dt][lane] holds
// Vt[d=dt*16+(lane&15)][j = jt*32 + (lane>>4)*8 .. +8] as 8 bf16. This makes
// the GEMM epilogue store coalesced (wave tiles a contiguous 512B region) AND
// the flash staging read linear (base + lane*16) — one layout, both kernels.

typedef __attribute__((ext_vector_type(8))) short short8;
typedef __attribute__((ext_vector_type(4))) float f32x4;

static __device__ __forceinline__ unsigned short f2bf(float x) {
    __hip_bfloat16 h = __float2bfloat16(x);
    return *reinterpret_cast<unsigned short*>(&h);
}

// packed f32->bf16 RNE, 2-at-a-time (T12: verified gfx950 mnemonic, no builtin)
static __device__ __forceinline__ unsigned cvtpk_bf16(float a, float b) {
    unsigned r;
    asm("v_cvt_pk_bf16_f32 %0, %1, %2" : "=v"(r) : "v"(a), "v"(b));
    return r;
}

// ---------------- K0: bf16 cast of data/W + conn edge-bitmask scan -----------
// (unchanged — pure streaming; counters next round will price it exactly)
__global__ __launch_bounds__(256) void k_cast_scan(const float* __restrict__ inA,
                                                   unsigned short* __restrict__ outA,
                                                   int n4A,
                                                   const float* __restrict__ inB,
                                                   unsigned short* __restrict__ outB,
                                                   int n4B,
                                                   const float* __restrict__ conn,
                                                   unsigned long long* __restrict__ bm) {
    if (blockIdx.x >= CAST_WGS) {
        const int lane = threadIdx.x & 63;
        const int w = threadIdx.x >> 6;
        const int row = (blockIdx.x - CAST_WGS) * 4 + w;
        const float* crow = conn + (size_t)row * NN;
        unsigned long long keep = 0;
#pragma unroll 8
        for (int t = 0; t < 64; t++) {
            float c = crow[t * 64 + lane];                 // 256B coalesced
            unsigned long long m = __ballot(c == 0.0f);    // kept edge == 0.0f
            if (lane == t) keep = m;
        }
        bm[(size_t)row * 64 + lane] = keep;                // 512B coalesced
        return;
    }
    int t = blockIdx.x * 256 + threadIdx.x;
    const float* in;
    unsigned short* out;
    if (t < n4A) {
        in = inA; out = outA;
    } else {
        t -= n4A;
        if (t >= n4B) return;
        in = inB; out = outB;
    }
    float4 v = ((const float4*)in)[t];
    ushort4 o;
    o.x = f2bf(v.x); o.y = f2bf(v.y); o.z = f2bf(v.z); o.w = f2bf(v.w);
    ((ushort4*)out)[t] = o;
}

// ---------------- K1: GEMM (bf16 MFMA) + fused src/trg projection ------------
// Main loop unchanged (R0-verified). Epilogue now stores d1t in fragment order:
// thread (col,quad) holds j = n0+w*16+quad*4+{0..3} for d = mt*16+col, which is
// exactly the (quad&1) 8B half of fragment chunk [h][jt][mt][kqf*16+col],
// jt = n0/32 + (w>>1), kqf = (w&1)*2 + (quad>>1). A wave's 64x8B stores tile
// one contiguous 512B region (vs R2/R3's 8KB-strided scatter).
__global__ __launch_bounds__(256) void k_gemm_fused(const unsigned short* __restrict__ Ab,
                                                    const unsigned short* __restrict__ Wb,
                                                    const float* __restrict__ bias,
                                                    const float* __restrict__ sp,
                                                    const float* __restrict__ tp,
                                                    unsigned short* __restrict__ d1t,
                                                    float* __restrict__ srcT,
                                                    float* __restrict__ trgT) {
    const int lane = threadIdx.x & 63;
    const int w = threadIdx.x >> 6;
    const int col = lane & 15;
    const int quad = lane >> 4;
    const int koff = quad * 8;
    const int h = blockIdx.x;
    const int m0 = h * 64;
    const int n0 = blockIdx.y * 64;

    const short8* ap  = (const short8*)(Ab + (size_t)(n0 + w * 16 + col) * IN_DIM + koff);
    const short8* bp0 = (const short8*)(Wb + (size_t)(m0 +  0 + col) * IN_DIM + koff);
    const short8* bp1 = (const short8*)(Wb + (size_t)(m0 + 16 + col) * IN_DIM + koff);
    const short8* bp2 = (const short8*)(Wb + (size_t)(m0 + 32 + col) * IN_DIM + koff);
    const short8* bp3 = (const short8*)(Wb + (size_t)(m0 + 48 + col) * IN_DIM + koff);

    f32x4 acc0 = {0.f, 0.f, 0.f, 0.f}, acc1 = acc0, acc2 = acc0, acc3 = acc0;

#pragma unroll 4
    for (int ks = 0; ks < 16; ks++) {
        short8 a  = ap[ks * 4];
        short8 b0 = bp0[ks * 4];
        short8 b1 = bp1[ks * 4];
        short8 b2 = bp2[ks * 4];
        short8 b3 = bp3[ks * 4];
        acc0 = __builtin_amdgcn_mfma_f32_16x16x32_bf16(a, b0, acc0, 0, 0, 0);
        acc1 = __builtin_amdgcn_mfma_f32_16x16x32_bf16(a, b1, acc1, 0, 0, 0);
        acc2 = __builtin_amdgcn_mfma_f32_16x16x32_bf16(a, b2, acc2, 0, 0, 0);
        acc3 = __builtin_amdgcn_mfma_f32_16x16x32_bf16(a, b3, acc3, 0, 0, 0);
    }

    const int rbase = n0 + w * 16 + quad * 4;
    const int jt  = (n0 >> 5) + (w >> 1);
    const int kqf = ((w & 1) << 1) + (quad >> 1);
    const int half = quad & 1;
    f32x4 accs[4] = {acc0, acc1, acc2, acc3};
    float ps[4] = {0.f, 0.f, 0.f, 0.f};
    float pt[4] = {0.f, 0.f, 0.f, 0.f};
#pragma unroll
    for (int mt = 0; mt < 4; mt++) {
        const int m = m0 + mt * 16 + col;
        const float bv  = bias[m];
        const float spv = sp[m];
        const float tpv = tp[m];
        ushort4 pack;
        unsigned short* pk = (unsigned short*)&pack;
#pragma unroll
        for (int r = 0; r < 4; r++) {
            float v = accs[mt][r] + bv;
            pk[r] = f2bf(v);
            ps[r] += v * spv;
            pt[r] += v * tpv;
        }
        size_t boff = ((((size_t)(h * 128 + jt) * 4 + mt) * 64 + kqf * 16 + col) << 4)
                    + ((size_t)half << 3);
        *(ushort4*)((char*)d1t + boff) = pack;
    }
#pragma unroll
    for (int off = 1; off <= 8; off <<= 1) {
#pragma unroll
        for (int r = 0; r < 4; r++) {
            ps[r] += __shfl_xor(ps[r], off, 64);
            pt[r] += __shfl_xor(pt[r], off, 64);
        }
    }
    if (col < 4)
        srcT[(size_t)h * NN + rbase + col] = ps[col] * LOG2E;
    else if (col < 8)
        trgT[(size_t)h * NN + rbase + col - 4] = pt[col - 4] * LOG2E;
}

// ---------------- K2: dense flash attention, fragment-ordered LDS (v3) -------
// R3 post-mortem: 1875 cy/jt (barrier every jt + vmcnt serialization) and a
// residual 4-way LDS conflict (SQ_LDS_BANK_CONFLICT = 4/read).
// v3: super-tile = 4 jt per barrier; per step, loads issue oldest-first
// {bm uint4, 8 t-float4, 4 stage-uint4} so per-use vmcnt(N) keeps staging in
// flight; Vt LDS is fragment-ordered (addr = base + lane*16 for BOTH write and
// read -> zero bank conflicts, zero swizzle). Denominator = 5th MFMA against a
// ones B-fragment: lane (kq,col) reg r gets rowsum(kq*4+r) — exactly the row
// this lane normalizes/stores; drops 8 VALU adds/jt + the shfl reduce.
// P->bf16 via v_cvt_pk_bf16_f32 (4 inst vs ~30).
__global__ __launch_bounds__(256) void k_flash(const unsigned* __restrict__ bm32,
                                               const float* __restrict__ srcT,
                                               const float* __restrict__ trgT,
                                               const unsigned short* __restrict__ d1t,
                                               float* __restrict__ out) {
    __shared__ char vt[2][16384];           // 2 x (4 jt x 4 dt x 64 lanes x 16B)

    const int t = threadIdx.x;
    const int lane = t & 63;
    const int w = t >> 6;
    const int col = lane & 15;
    const int kq = lane >> 4;
    const int i0 = blockIdx.x * 64;
    const int h = blockIdx.y;
    const int m = i0 + w * 16 + col;        // this lane's P row

    const float s = srcT[(size_t)h * NN + m];
    const unsigned* bp = bm32 + (size_t)m * 128;
    const float* tpp = trgT + (size_t)h * NN + kq * 8;
    // staging: wave w stages dt=w; chunk (jt, w, lane) from fragment-ordered
    // global: uint4 index = ((h*128 + jt)*4 + w)*64 + lane  -> linear reads.
    const uint4* gfrag = (const uint4*)d1t + (((size_t)h * 128) * 4 + w) * 64 + lane;
    const short8 ONES = {0x3F80, 0x3F80, 0x3F80, 0x3F80, 0x3F80, 0x3F80, 0x3F80, 0x3F80};

    f32x4 acc0 = {0.f, 0.f, 0.f, 0.f}, acc1 = acc0, acc2 = acc0, acc3 = acc0;
    f32x4 asum = acc0;

    // prologue: stage step 0 (jt 0..3)
#pragma unroll
    for (int i = 0; i < 4; i++) {
        uint4 st = gfrag[(size_t)i * 256];               // jt=i
        *(uint4*)(vt[0] + ((i * 4 + w) * 64 + lane) * 16) = st;
    }
    __syncthreads();

    for (int step = 0; step < 32; step++) {
        const int cur = step & 1;
        // ---- issue this step's loads oldest-first ----
        uint4 bq = *(const uint4*)(bp + step * 4);       // 4 bitmask words
        float4 tA[4], tB[4];
#pragma unroll
        for (int jtl = 0; jtl < 4; jtl++) {
            tA[jtl] = *(const float4*)(tpp + (step * 4 + jtl) * 32);
            tB[jtl] = *(const float4*)(tpp + (step * 4 + jtl) * 32 + 4);
        }
        uint4 st0, st1, st2, st3;
        if (step < 31) {
            const uint4* gs = gfrag + (size_t)(step + 1) * 4 * 256;
            st0 = gs[0]; st1 = gs[256]; st2 = gs[512]; st3 = gs[768];
        }
        const unsigned bqa[4] = {bq.x, bq.y, bq.z, bq.w};

        // ---- compute 4 jt from buf[cur] (no barriers inside) ----
#pragma unroll
        for (int jtl = 0; jtl < 4; jtl++) {
            const unsigned bits = (bqa[jtl] >> (kq * 8)) & 0xffu;
            const float tv[8] = {tA[jtl].x, tA[jtl].y, tA[jtl].z, tA[jtl].w,
                                 tB[jtl].x, tB[jtl].y, tB[jtl].z, tB[jtl].w};
            float p[8];
#pragma unroll
            for (int r = 0; r < 8; r++) {
                float e = s + tv[r];
                e = fmaxf(e, 0.01f * e);                 // LeakyReLU (log2-scaled)
                float pv = __builtin_amdgcn_exp2f(e);
                pv *= (float)((bits >> r) & 1u);         // exact 0 for non-edge
                p[r] = pv;
            }
            union { uint4 u; short8 s8; } pk;
            pk.u.x = cvtpk_bf16(p[0], p[1]);
            pk.u.y = cvtpk_bf16(p[2], p[3]);
            pk.u.z = cvtpk_bf16(p[4], p[5]);
            pk.u.w = cvtpk_bf16(p[6], p[7]);
            const char* cb = vt[cur] + (jtl * 4 * 64) * 16 + lane * 16;
            short8 v0 = *(const short8*)(cb);
            short8 v1 = *(const short8*)(cb + 1024);
            short8 v2 = *(const short8*)(cb + 2048);
            short8 v3 = *(const short8*)(cb + 3072);
            acc0 = __builtin_amdgcn_mfma_f32_16x16x32_bf16(pk.s8, v0, acc0, 0, 0, 0);
            acc1 = __builtin_amdgcn_mfma_f32_16x16x32_bf16(pk.s8, v1, acc1, 0, 0, 0);
            acc2 = __builtin_amdgcn_mfma_f32_16x16x32_bf16(pk.s8, v2, acc2, 0, 0, 0);
            acc3 = __builtin_amdgcn_mfma_f32_16x16x32_bf16(pk.s8, v3, acc3, 0, 0, 0);
            asum = __builtin_amdgcn_mfma_f32_16x16x32_bf16(pk.s8, ONES, asum, 0, 0, 0);
        }

        // ---- write-late staged tile into buf[cur^1], one barrier ----
        if (step < 31) {
            char* wbuf = vt[cur ^ 1];
            *(uint4*)(wbuf + ((0 * 4 + w) * 64 + lane) * 16) = st0;
            *(uint4*)(wbuf + ((1 * 4 + w) * 64 + lane) * 16) = st1;
            *(uint4*)(wbuf + ((2 * 4 + w) * 64 + lane) * 16) = st2;
            *(uint4*)(wbuf + ((3 * 4 + w) * 64 + lane) * 16) = st3;
        }
        __syncthreads();
    }

    // ---- normalize + store: lane (kq,col) has den(row kq*4+r) in asum[r] ----
    f32x4 accs[4] = {acc0, acc1, acc2, acc3};
#pragma unroll
    for (int r = 0; r < 4; r++) {
        const int row = i0 + w * 16 + kq * 4 + r;
        const float dv = asum[r];
        const float inv = (dv > 0.f) ? (1.f / dv) : 0.f;
        float* op = out + (size_t)row * HD + h * 64;
#pragma unroll
        for (int dt = 0; dt < 4; dt++)
            op[dt * 16 + col] = accs[dt][r] * inv;
    }
}

extern "C" void kernel_launch(void* const* d_in, const int* in_sizes, int n_in,
                              void* d_out, int out_size, void* d_ws, size_t ws_size,
                              hipStream_t stream) {
    const float* data = (const float*)d_in[0];   // (4096, 512)
    const float* conn = (const float*)d_in[1];   // (4096, 4096)
    const float* W    = (const float*)d_in[2];   // (512, 512)
    const float* bias = (const float*)d_in[3];   // (512,)
    const float* sp   = (const float*)d_in[4];   // (1, 8, 64)
    const float* tp   = (const float*)d_in[5];   // (1, 8, 64)
    float* out = (float*)d_out;                  // (4096, 512) fp32

    unsigned short* d1t = (unsigned short*)d_ws;              // 4 MB, fragment order
    unsigned short* Ab  = d1t + (size_t)HD * NN;              // 4 MB
    unsigned short* Wb  = Ab + (size_t)NN * IN_DIM;           // 512 KB
    float* srcT = (float*)(Wb + (size_t)HD * IN_DIM);         // 128 KB
    float* trgT = srcT + NH * NN;                             // 128 KB
    unsigned long long* bm = (unsigned long long*)(trgT + NH * NN); // 2 MB
    // total ~10.75 MB

    const int n4A = NN * IN_DIM / 4;   // 524288
    const int n4B = HD * IN_DIM / 4;   // 65536
    k_cast_scan<<<dim3(CAST_WGS + SCAN_WGS), 256, 0, stream>>>(data, Ab, n4A, W, Wb, n4B,
                                                               conn, bm);
    k_gemm_fused<<<dim3(NH, NN / 64), 256, 0, stream>>>(Ab, Wb, bias, sp, tp,
                                                        d1t, srcT, trgT);
    k_flash<<<dim3(64, NH), 256, 0, stream>>>((const unsigned*)bm, srcT, trgT, d1t, out);
}

// Round 5
// 184.346 us; speedup vs baseline: 2.0966x; 1.0168x over previous
//
#include <hip/hip_runtime.h>
#include <hip/hip_bf16.h>

#define NN 4096
#define IN_DIM 512
#define NH 8
#define DD 64
#define HD 512    // NH*DD
#define LOG2E 1.4426950408889634f
#define CAST_WGS 2304   // (524288+65536)/256 exactly
#define SCAN_WGS 1024

// Workspace: d1t 4MB + Ab 4MB + Wb 0.5MB + srcT/trgT 0.25MB + bm 2MB = 10.75 MB
// d1t is stored in FRAGMENT ORDER: 16B chunk index [h][jt][dt][lane] holds
// Vt[d=dt*16+(lane&15)][j = jt*32 + (lane>>4)*8 .. +8] as 8 bf16.

typedef __attribute__((ext_vector_type(8))) short short8;
typedef __attribute__((ext_vector_type(4))) float f32x4;

static __device__ __forceinline__ unsigned short f2bf(float x) {
    __hip_bfloat16 h = __float2bfloat16(x);
    return *reinterpret_cast<unsigned short*>(&h);
}

// packed f32->bf16 RNE, 2-at-a-time (T12: verified gfx950 mnemonic, no builtin)
static __device__ __forceinline__ unsigned cvtpk_bf16(float a, float b) {
    unsigned r;
    asm("v_cvt_pk_bf16_f32 %0, %1, %2" : "=v"(r) : "v"(a), "v"(b));
    return r;
}

// ---------------- K0: bf16 cast of data/W + conn edge-bitmask scan -----------
// (unchanged from R4)
__global__ __launch_bounds__(256) void k_cast_scan(const float* __restrict__ inA,
                                                   unsigned short* __restrict__ outA,
                                                   int n4A,
                                                   const float* __restrict__ inB,
                                                   unsigned short* __restrict__ outB,
                                                   int n4B,
                                                   const float* __restrict__ conn,
                                                   unsigned long long* __restrict__ bm) {
    if (blockIdx.x >= CAST_WGS) {
        const int lane = threadIdx.x & 63;
        const int w = threadIdx.x >> 6;
        const int row = (blockIdx.x - CAST_WGS) * 4 + w;
        const float* crow = conn + (size_t)row * NN;
        unsigned long long keep = 0;
#pragma unroll 8
        for (int t = 0; t < 64; t++) {
            float c = crow[t * 64 + lane];                 // 256B coalesced
            unsigned long long m = __ballot(c == 0.0f);    // kept edge == 0.0f
            if (lane == t) keep = m;
        }
        bm[(size_t)row * 64 + lane] = keep;                // 512B coalesced
        return;
    }
    int t = blockIdx.x * 256 + threadIdx.x;
    const float* in;
    unsigned short* out;
    if (t < n4A) {
        in = inA; out = outA;
    } else {
        t -= n4A;
        if (t >= n4B) return;
        in = inB; out = outB;
    }
    float4 v = ((const float4*)in)[t];
    ushort4 o;
    o.x = f2bf(v.x); o.y = f2bf(v.y); o.z = f2bf(v.z); o.w = f2bf(v.w);
    ((ushort4*)out)[t] = o;
}

// ---------------- K1: GEMM (bf16 MFMA) + fused src/trg projection ------------
// (unchanged from R4 — fragment-order d1t epilogue, srcT/trgT pre-scaled LOG2E)
__global__ __launch_bounds__(256) void k_gemm_fused(const unsigned short* __restrict__ Ab,
                                                    const unsigned short* __restrict__ Wb,
                                                    const float* __restrict__ bias,
                                                    const float* __restrict__ sp,
                                                    const float* __restrict__ tp,
                                                    unsigned short* __restrict__ d1t,
                                                    float* __restrict__ srcT,
                                                    float* __restrict__ trgT) {
    const int lane = threadIdx.x & 63;
    const int w = threadIdx.x >> 6;
    const int col = lane & 15;
    const int quad = lane >> 4;
    const int koff = quad * 8;
    const int h = blockIdx.x;
    const int m0 = h * 64;
    const int n0 = blockIdx.y * 64;

    const short8* ap  = (const short8*)(Ab + (size_t)(n0 + w * 16 + col) * IN_DIM + koff);
    const short8* bp0 = (const short8*)(Wb + (size_t)(m0 +  0 + col) * IN_DIM + koff);
    const short8* bp1 = (const short8*)(Wb + (size_t)(m0 + 16 + col) * IN_DIM + koff);
    const short8* bp2 = (const short8*)(Wb + (size_t)(m0 + 32 + col) * IN_DIM + koff);
    const short8* bp3 = (const short8*)(Wb + (size_t)(m0 + 48 + col) * IN_DIM + koff);

    f32x4 acc0 = {0.f, 0.f, 0.f, 0.f}, acc1 = acc0, acc2 = acc0, acc3 = acc0;

#pragma unroll 4
    for (int ks = 0; ks < 16; ks++) {
        short8 a  = ap[ks * 4];
        short8 b0 = bp0[ks * 4];
        short8 b1 = bp1[ks * 4];
        short8 b2 = bp2[ks * 4];
        short8 b3 = bp3[ks * 4];
        acc0 = __builtin_amdgcn_mfma_f32_16x16x32_bf16(a, b0, acc0, 0, 0, 0);
        acc1 = __builtin_amdgcn_mfma_f32_16x16x32_bf16(a, b1, acc1, 0, 0, 0);
        acc2 = __builtin_amdgcn_mfma_f32_16x16x32_bf16(a, b2, acc2, 0, 0, 0);
        acc3 = __builtin_amdgcn_mfma_f32_16x16x32_bf16(a, b3, acc3, 0, 0, 0);
    }

    const int rbase = n0 + w * 16 + quad * 4;
    const int jt  = (n0 >> 5) + (w >> 1);
    const int kqf = ((w & 1) << 1) + (quad >> 1);
    const int half = quad & 1;
    f32x4 accs[4] = {acc0, acc1, acc2, acc3};
    float ps[4] = {0.f, 0.f, 0.f, 0.f};
    float pt[4] = {0.f, 0.f, 0.f, 0.f};
#pragma unroll
    for (int mt = 0; mt < 4; mt++) {
        const int m = m0 + mt * 16 + col;
        const float bv  = bias[m];
        const float spv = sp[m];
        const float tpv = tp[m];
        ushort4 pack;
        unsigned short* pk = (unsigned short*)&pack;
#pragma unroll
        for (int r = 0; r < 4; r++) {
            float v = accs[mt][r] + bv;
            pk[r] = f2bf(v);
            ps[r] += v * spv;
            pt[r] += v * tpv;
        }
        size_t boff = ((((size_t)(h * 128 + jt) * 4 + mt) * 64 + kqf * 16 + col) << 4)
                    + ((size_t)half << 3);
        *(ushort4*)((char*)d1t + boff) = pack;
    }
#pragma unroll
    for (int off = 1; off <= 8; off <<= 1) {
#pragma unroll
        for (int r = 0; r < 4; r++) {
            ps[r] += __shfl_xor(ps[r], off, 64);
            pt[r] += __shfl_xor(pt[r], off, 64);
        }
    }
    if (col < 4)
        srcT[(size_t)h * NN + rbase + col] = ps[col] * LOG2E;
    else if (col < 8)
        trgT[(size_t)h * NN + rbase + col - 4] = pt[col - 4] * LOG2E;
}

// ---------------- K2: dense flash attention, deep-pipelined (v4) -------------
// R4 post-mortem: 65us vs ~18us work model. (a) 512 blocks re-read d1t 256MB
// through a thrashing 4MB L2; (b) step-top loads consumed in-step under an
// if(step<31) branch -> exposed L2 latency every step.
// v4: 128-row blocks (grid 32x8, 512 thr, 8 waves share the Vt tile) halve
// d1t traffic to 128MB; depth-1 REGISTER pipeline for everything: staging regs
// (st0/st1) hold step+1's tile, scalar regs (bm uint4 + 8 float4 t) are c/n
// double-buffered with #pragma unroll 2 so rotation is pure renaming. Every
// global load is issued >= 1 full step (~700cy) before use, unconditionally
// (clamped index — no branch for the compiler to sink loads into).
__global__ __launch_bounds__(512) void k_flash(const unsigned* __restrict__ bm32,
                                               const float* __restrict__ srcT,
                                               const float* __restrict__ trgT,
                                               const unsigned short* __restrict__ d1t,
                                               float* __restrict__ out) {
    __shared__ char vt[2][16384];           // 2 x (4 jt x 4 dt x 64 lanes x 16B)

    const int t = threadIdx.x;              // 0..511
    const int lane = t & 63;
    const int w = t >> 6;                   // 0..7
    const int col = lane & 15;
    const int kq = lane >> 4;
    const int i0 = blockIdx.x * 128;
    const int h = blockIdx.y;
    const int m = i0 + w * 16 + col;        // this lane's P row

    const float s = srcT[(size_t)h * NN + m];
    const unsigned* bp = bm32 + (size_t)m * 128;
    const float* tpp = trgT + (size_t)h * NN + kq * 8;
    const uint4* gv = (const uint4*)d1t + (size_t)h * 32768;  // 128jt x 256 chunks
    const short8 ONES = {0x3F80, 0x3F80, 0x3F80, 0x3F80, 0x3F80, 0x3F80, 0x3F80, 0x3F80};

    f32x4 acc0 = {0.f, 0.f, 0.f, 0.f}, acc1 = acc0, acc2 = acc0, acc3 = acc0;
    f32x4 asum = acc0;

    // ---- prologue: tile0 -> LDS[0]; tile1 -> staging regs; scalars 0->c, 1->n
    {
        uint4 a0 = gv[t];
        uint4 a1 = gv[t + 512];
        *(uint4*)(vt[0] + (size_t)t * 16) = a0;
        *(uint4*)(vt[0] + (size_t)(t + 512) * 16) = a1;
    }
    uint4 st0 = gv[1024 + t];
    uint4 st1 = gv[1024 + t + 512];
    uint4 bq_c = *(const uint4*)(bp);
    uint4 bq_n = *(const uint4*)(bp + 4);
    float4 tAc[4], tBc[4], tAn[4], tBn[4];
#pragma unroll
    for (int jtl = 0; jtl < 4; jtl++) {
        tAc[jtl] = *(const float4*)(tpp + jtl * 32);
        tBc[jtl] = *(const float4*)(tpp + jtl * 32 + 4);
        tAn[jtl] = *(const float4*)(tpp + (4 + jtl) * 32);
        tBn[jtl] = *(const float4*)(tpp + (4 + jtl) * 32 + 4);
    }
    __syncthreads();

#pragma unroll 2
    for (int step = 0; step < 32; step++) {
        const int cur = step & 1;
        // 1. write step+1's staged tile into the other buffer (regs loaded
        //    a full step ago -> cheap vmcnt); visible after this step's barrier
        char* wb = vt[cur ^ 1];
        *(uint4*)(wb + (size_t)t * 16) = st0;
        *(uint4*)(wb + (size_t)(t + 512) * 16) = st1;
        // 2. issue step+2 staging loads (clamped; tail loads are unused)
        const int s2 = (step + 2 < 32) ? step + 2 : 31;
        st0 = gv[s2 * 1024 + t];
        st1 = gv[s2 * 1024 + t + 512];

        // 3. compute 4 jt from LDS[cur] with c-scalars (loaded a step ago)
        const unsigned bqa[4] = {bq_c.x, bq_c.y, bq_c.z, bq_c.w};
#pragma unroll
        for (int jtl = 0; jtl < 4; jtl++) {
            const unsigned bits = (bqa[jtl] >> (kq * 8)) & 0xffu;
            const float tv[8] = {tAc[jtl].x, tAc[jtl].y, tAc[jtl].z, tAc[jtl].w,
                                 tBc[jtl].x, tBc[jtl].y, tBc[jtl].z, tBc[jtl].w};
            float p[8];
#pragma unroll
            for (int r = 0; r < 8; r++) {
                float e = s + tv[r];
                e = fmaxf(e, 0.01f * e);                 // LeakyReLU (log2-scaled)
                float pv = __builtin_amdgcn_exp2f(e);
                pv *= (float)((bits >> r) & 1u);         // exact 0 for non-edge
                p[r] = pv;
            }
            union { uint4 u; short8 s8; } pk;
            pk.u.x = cvtpk_bf16(p[0], p[1]);
            pk.u.y = cvtpk_bf16(p[2], p[3]);
            pk.u.z = cvtpk_bf16(p[4], p[5]);
            pk.u.w = cvtpk_bf16(p[6], p[7]);
            const char* cb = vt[cur] + jtl * 4096 + lane * 16;
            short8 v0 = *(const short8*)(cb);
            short8 v1 = *(const short8*)(cb + 1024);
            short8 v2 = *(const short8*)(cb + 2048);
            short8 v3 = *(const short8*)(cb + 3072);
            acc0 = __builtin_amdgcn_mfma_f32_16x16x32_bf16(pk.s8, v0, acc0, 0, 0, 0);
            acc1 = __builtin_amdgcn_mfma_f32_16x16x32_bf16(pk.s8, v1, acc1, 0, 0, 0);
            acc2 = __builtin_amdgcn_mfma_f32_16x16x32_bf16(pk.s8, v2, acc2, 0, 0, 0);
            acc3 = __builtin_amdgcn_mfma_f32_16x16x32_bf16(pk.s8, v3, acc3, 0, 0, 0);
            asum = __builtin_amdgcn_mfma_f32_16x16x32_bf16(pk.s8, ONES, asum, 0, 0, 0);
        }

        // 4. rotate scalars (renames under unroll 2) and issue step+2 loads
        bq_c = bq_n;
#pragma unroll
        for (int jtl = 0; jtl < 4; jtl++) { tAc[jtl] = tAn[jtl]; tBc[jtl] = tBn[jtl]; }
        bq_n = *(const uint4*)(bp + s2 * 4);
#pragma unroll
        for (int jtl = 0; jtl < 4; jtl++) {
            tAn[jtl] = *(const float4*)(tpp + (s2 * 4 + jtl) * 32);
            tBn[jtl] = *(const float4*)(tpp + (s2 * 4 + jtl) * 32 + 4);
        }
        __syncthreads();
    }

    // ---- normalize + store: lane (kq,col) has den(row kq*4+r) in asum[r] ----
    f32x4 accs[4] = {acc0, acc1, acc2, acc3};
#pragma unroll
    for (int r = 0; r < 4; r++) {
        const int row = i0 + w * 16 + kq * 4 + r;
        const float dv = asum[r];
        const float inv = (dv > 0.f) ? (1.f / dv) : 0.f;
        float* op = out + (size_t)row * HD + h * 64;
#pragma unroll
        for (int dt = 0; dt < 4; dt++)
            op[dt * 16 + col] = accs[dt][r] * inv;
    }
}

extern "C" void kernel_launch(void* const* d_in, const int* in_sizes, int n_in,
                              void* d_out, int out_size, void* d_ws, size_t ws_size,
                              hipStream_t stream) {
    const float* data = (const float*)d_in[0];   // (4096, 512)
    const float* conn = (const float*)d_in[1];   // (4096, 4096)
    const float* W    = (const float*)d_in[2];   // (512, 512)
    const float* bias = (const float*)d_in[3];   // (512,)
    const float* sp   = (const float*)d_in[4];   // (1, 8, 64)
    const float* tp   = (const float*)d_in[5];   // (1, 8, 64)
    float* out = (float*)d_out;                  // (4096, 512) fp32

    unsigned short* d1t = (unsigned short*)d_ws;              // 4 MB, fragment order
    unsigned short* Ab  = d1t + (size_t)HD * NN;              // 4 MB
    unsigned short* Wb  = Ab + (size_t)NN * IN_DIM;           // 512 KB
    float* srcT = (float*)(Wb + (size_t)HD * IN_DIM);         // 128 KB
    float* trgT = srcT + NH * NN;                             // 128 KB
    unsigned long long* bm = (unsigned long long*)(trgT + NH * NN); // 2 MB
    // total ~10.75 MB

    const int n4A = NN * IN_DIM / 4;   // 524288
    const int n4B = HD * IN_DIM / 4;   // 65536
    k_cast_scan<<<dim3(CAST_WGS + SCAN_WGS), 256, 0, stream>>>(data, Ab, n4A, W, Wb, n4B,
                                                               conn, bm);
    k_gemm_fused<<<dim3(NH, NN / 64), 256, 0, stream>>>(Ab, Wb, bias, sp, tp,
                                                        d1t, srcT, trgT);
    k_flash<<<dim3(NN / 128, NH), 512, 0, stream>>>((const unsigned*)bm, srcT, trgT, d1t, out);
}

// Round 6
// 183.620 us; speedup vs baseline: 2.1048x; 1.0040x over previous
//
#include <hip/hip_runtime.h>
#include <hip/hip_bf16.h>

#define NN 4096
#define IN_DIM 512
#define NH 8
#define DD 64
#define HD 512    // NH*DD
#define LOG2E 1.4426950408889634f
#define CAST_WGS 2304   // (524288+65536)/256 exactly
#define SCAN_WGS 1024

// Workspace: d1t 4MB + Ab 4MB + Wb 0.5MB + srcT/trgT 0.25MB + bm 2MB = 10.75 MB
// d1t is stored in FRAGMENT ORDER: 16B chunk index [h][jt][dt][lane] holds
// Vt[d=dt*16+(lane&15)][j = jt*32 + (lane>>4)*8 .. +8] as 8 bf16.

typedef __attribute__((ext_vector_type(8))) short short8;
typedef __attribute__((ext_vector_type(4))) float f32x4;

static __device__ __forceinline__ unsigned short f2bf(float x) {
    __hip_bfloat16 h = __float2bfloat16(x);
    return *reinterpret_cast<unsigned short*>(&h);
}

// packed f32->bf16 RNE, 2-at-a-time (T12: verified gfx950 mnemonic, no builtin)
static __device__ __forceinline__ unsigned cvtpk_bf16(float a, float b) {
    unsigned r;
    asm("v_cvt_pk_bf16_f32 %0, %1, %2" : "=v"(r) : "v"(a), "v"(b));
    return r;
}

// ---------------- K0: bf16 cast of data/W + conn edge-bitmask scan -----------
// (frozen — control for this round)
__global__ __launch_bounds__(256) void k_cast_scan(const float* __restrict__ inA,
                                                   unsigned short* __restrict__ outA,
                                                   int n4A,
                                                   const float* __restrict__ inB,
                                                   unsigned short* __restrict__ outB,
                                                   int n4B,
                                                   const float* __restrict__ conn,
                                                   unsigned long long* __restrict__ bm) {
    if (blockIdx.x >= CAST_WGS) {
        const int lane = threadIdx.x & 63;
        const int w = threadIdx.x >> 6;
        const int row = (blockIdx.x - CAST_WGS) * 4 + w;
        const float* crow = conn + (size_t)row * NN;
        unsigned long long keep = 0;
#pragma unroll 8
        for (int t = 0; t < 64; t++) {
            float c = crow[t * 64 + lane];                 // 256B coalesced
            unsigned long long m = __ballot(c == 0.0f);    // kept edge == 0.0f
            if (lane == t) keep = m;
        }
        bm[(size_t)row * 64 + lane] = keep;                // 512B coalesced
        return;
    }
    int t = blockIdx.x * 256 + threadIdx.x;
    const float* in;
    unsigned short* out;
    if (t < n4A) {
        in = inA; out = outA;
    } else {
        t -= n4A;
        if (t >= n4B) return;
        in = inB; out = outB;
    }
    float4 v = ((const float4*)in)[t];
    ushort4 o;
    o.x = f2bf(v.x); o.y = f2bf(v.y); o.z = f2bf(v.z); o.w = f2bf(v.w);
    ((ushort4*)out)[t] = o;
}

// ---------------- K1: split-K GEMM (bf16 MFMA) + fused src/trg projection ----
// R5 theory: GEMM is latency-bound at 2 waves/SIMD (every fragment a dependent
// ~250cy L2 load). v2: 8 waves/block; waves 0-3 do K[0,256), waves 4-7 do
// K[256,512) for the SAME 64n x 64m tile -> 4096 waves = 4 waves/SIMD, zero
// redundant loads, per-wave dependent-load chain halved (40 loads). Halves
// combined via one 16KB LDS exchange (f32x4 at lane-stride 16B — the pattern
// R5's counters proved conflict-free) + one barrier. Epilogue (fragment-order
// d1t store + LOG2E-scaled srcT/trgT projections) unchanged, on waves 0-3.
__global__ __launch_bounds__(512) void k_gemm_fused(const unsigned short* __restrict__ Ab,
                                                    const unsigned short* __restrict__ Wb,
                                                    const float* __restrict__ bias,
                                                    const float* __restrict__ sp,
                                                    const float* __restrict__ tp,
                                                    unsigned short* __restrict__ d1t,
                                                    float* __restrict__ srcT,
                                                    float* __restrict__ trgT) {
    __shared__ f32x4 cbuf[4][4 * 64];     // 16KB: [row-quad][mt*64+lane]
    const int lane = threadIdx.x & 63;
    const int w8 = threadIdx.x >> 6;      // 0..7
    const int w  = w8 & 3;                // row-quad within tile
    const int kh = w8 >> 2;               // k-half: 0 -> K[0,256), 1 -> K[256,512)
    const int col = lane & 15;
    const int quad = lane >> 4;
    const int koff = quad * 8 + kh * 256;
    const int h = blockIdx.x;
    const int m0 = h * 64;
    const int n0 = blockIdx.y * 64;

    const short8* ap  = (const short8*)(Ab + (size_t)(n0 + w * 16 + col) * IN_DIM + koff);
    const short8* bp0 = (const short8*)(Wb + (size_t)(m0 +  0 + col) * IN_DIM + koff);
    const short8* bp1 = (const short8*)(Wb + (size_t)(m0 + 16 + col) * IN_DIM + koff);
    const short8* bp2 = (const short8*)(Wb + (size_t)(m0 + 32 + col) * IN_DIM + koff);
    const short8* bp3 = (const short8*)(Wb + (size_t)(m0 + 48 + col) * IN_DIM + koff);

    f32x4 acc0 = {0.f, 0.f, 0.f, 0.f}, acc1 = acc0, acc2 = acc0, acc3 = acc0;

#pragma unroll 8
    for (int ks = 0; ks < 8; ks++) {
        short8 a  = ap[ks * 4];
        short8 b0 = bp0[ks * 4];
        short8 b1 = bp1[ks * 4];
        short8 b2 = bp2[ks * 4];
        short8 b3 = bp3[ks * 4];
        acc0 = __builtin_amdgcn_mfma_f32_16x16x32_bf16(a, b0, acc0, 0, 0, 0);
        acc1 = __builtin_amdgcn_mfma_f32_16x16x32_bf16(a, b1, acc1, 0, 0, 0);
        acc2 = __builtin_amdgcn_mfma_f32_16x16x32_bf16(a, b2, acc2, 0, 0, 0);
        acc3 = __builtin_amdgcn_mfma_f32_16x16x32_bf16(a, b3, acc3, 0, 0, 0);
    }

    // ---- combine k-halves: waves 4-7 deposit, one barrier, waves 0-3 add ----
    if (kh == 1) {
        cbuf[w][0 * 64 + lane] = acc0;
        cbuf[w][1 * 64 + lane] = acc1;
        cbuf[w][2 * 64 + lane] = acc2;
        cbuf[w][3 * 64 + lane] = acc3;
    }
    __syncthreads();
    if (kh == 1) return;
    acc0 += cbuf[w][0 * 64 + lane];
    acc1 += cbuf[w][1 * 64 + lane];
    acc2 += cbuf[w][2 * 64 + lane];
    acc3 += cbuf[w][3 * 64 + lane];

    const int rbase = n0 + w * 16 + quad * 4;
    const int jt  = (n0 >> 5) + (w >> 1);
    const int kqf = ((w & 1) << 1) + (quad >> 1);
    const int half = quad & 1;
    f32x4 accs[4] = {acc0, acc1, acc2, acc3};
    float ps[4] = {0.f, 0.f, 0.f, 0.f};
    float pt[4] = {0.f, 0.f, 0.f, 0.f};
#pragma unroll
    for (int mt = 0; mt < 4; mt++) {
        const int m = m0 + mt * 16 + col;
        const float bv  = bias[m];
        const float spv = sp[m];
        const float tpv = tp[m];
        ushort4 pack;
        unsigned short* pk = (unsigned short*)&pack;
#pragma unroll
        for (int r = 0; r < 4; r++) {
            float v = accs[mt][r] + bv;
            pk[r] = f2bf(v);
            ps[r] += v * spv;
            pt[r] += v * tpv;
        }
        size_t boff = ((((size_t)(h * 128 + jt) * 4 + mt) * 64 + kqf * 16 + col) << 4)
                    + ((size_t)half << 3);
        *(ushort4*)((char*)d1t + boff) = pack;
    }
#pragma unroll
    for (int off = 1; off <= 8; off <<= 1) {
#pragma unroll
        for (int r = 0; r < 4; r++) {
            ps[r] += __shfl_xor(ps[r], off, 64);
            pt[r] += __shfl_xor(pt[r], off, 64);
        }
    }
    if (col < 4)
        srcT[(size_t)h * NN + rbase + col] = ps[col] * LOG2E;
    else if (col < 8)
        trgT[(size_t)h * NN + rbase + col - 4] = pt[col - 4] * LOG2E;
}

// ---------------- K2: dense flash attention, deep-pipelined (v4) -------------
// (frozen — control for this round; R5: 58us, 0 bank conflicts)
__global__ __launch_bounds__(512) void k_flash(const unsigned* __restrict__ bm32,
                                               const float* __restrict__ srcT,
                                               const float* __restrict__ trgT,
                                               const unsigned short* __restrict__ d1t,
                                               float* __restrict__ out) {
    __shared__ char vt[2][16384];           // 2 x (4 jt x 4 dt x 64 lanes x 16B)

    const int t = threadIdx.x;              // 0..511
    const int lane = t & 63;
    const int w = t >> 6;                   // 0..7
    const int col = lane & 15;
    const int kq = lane >> 4;
    const int i0 = blockIdx.x * 128;
    const int h = blockIdx.y;
    const int m = i0 + w * 16 + col;        // this lane's P row

    const float s = srcT[(size_t)h * NN + m];
    const unsigned* bp = bm32 + (size_t)m * 128;
    const float* tpp = trgT + (size_t)h * NN + kq * 8;
    const uint4* gv = (const uint4*)d1t + (size_t)h * 32768;  // 128jt x 256 chunks
    const short8 ONES = {0x3F80, 0x3F80, 0x3F80, 0x3F80, 0x3F80, 0x3F80, 0x3F80, 0x3F80};

    f32x4 acc0 = {0.f, 0.f, 0.f, 0.f}, acc1 = acc0, acc2 = acc0, acc3 = acc0;
    f32x4 asum = acc0;

    // ---- prologue: tile0 -> LDS[0]; tile1 -> staging regs; scalars 0->c, 1->n
    {
        uint4 a0 = gv[t];
        uint4 a1 = gv[t + 512];
        *(uint4*)(vt[0] + (size_t)t * 16) = a0;
        *(uint4*)(vt[0] + (size_t)(t + 512) * 16) = a1;
    }
    uint4 st0 = gv[1024 + t];
    uint4 st1 = gv[1024 + t + 512];
    uint4 bq_c = *(const uint4*)(bp);
    uint4 bq_n = *(const uint4*)(bp + 4);
    float4 tAc[4], tBc[4], tAn[4], tBn[4];
#pragma unroll
    for (int jtl = 0; jtl < 4; jtl++) {
        tAc[jtl] = *(const float4*)(tpp + jtl * 32);
        tBc[jtl] = *(const float4*)(tpp + jtl * 32 + 4);
        tAn[jtl] = *(const float4*)(tpp + (4 + jtl) * 32);
        tBn[jtl] = *(const float4*)(tpp + (4 + jtl) * 32 + 4);
    }
    __syncthreads();

#pragma unroll 2
    for (int step = 0; step < 32; step++) {
        const int cur = step & 1;
        // 1. write step+1's staged tile into the other buffer
        char* wb = vt[cur ^ 1];
        *(uint4*)(wb + (size_t)t * 16) = st0;
        *(uint4*)(wb + (size_t)(t + 512) * 16) = st1;
        // 2. issue step+2 staging loads (clamped; tail loads are unused)
        const int s2 = (step + 2 < 32) ? step + 2 : 31;
        st0 = gv[s2 * 1024 + t];
        st1 = gv[s2 * 1024 + t + 512];

        // 3. compute 4 jt from LDS[cur] with c-scalars (loaded a step ago)
        const unsigned bqa[4] = {bq_c.x, bq_c.y, bq_c.z, bq_c.w};
#pragma unroll
        for (int jtl = 0; jtl < 4; jtl++) {
            const unsigned bits = (bqa[jtl] >> (kq * 8)) & 0xffu;
            const float tv[8] = {tAc[jtl].x, tAc[jtl].y, tAc[jtl].z, tAc[jtl].w,
                                 tBc[jtl].x, tBc[jtl].y, tBc[jtl].z, tBc[jtl].w};
            float p[8];
#pragma unroll
            for (int r = 0; r < 8; r++) {
                float e = s + tv[r];
                e = fmaxf(e, 0.01f * e);                 // LeakyReLU (log2-scaled)
                float pv = __builtin_amdgcn_exp2f(e);
                pv *= (float)((bits >> r) & 1u);         // exact 0 for non-edge
                p[r] = pv;
            }
            union { uint4 u; short8 s8; } pk;
            pk.u.x = cvtpk_bf16(p[0], p[1]);
            pk.u.y = cvtpk_bf16(p[2], p[3]);
            pk.u.z = cvtpk_bf16(p[4], p[5]);
            pk.u.w = cvtpk_bf16(p[6], p[7]);
            const char* cb = vt[cur] + jtl * 4096 + lane * 16;
            short8 v0 = *(const short8*)(cb);
            short8 v1 = *(const short8*)(cb + 1024);
            short8 v2 = *(const short8*)(cb + 2048);
            short8 v3 = *(const short8*)(cb + 3072);
            acc0 = __builtin_amdgcn_mfma_f32_16x16x32_bf16(pk.s8, v0, acc0, 0, 0, 0);
            acc1 = __builtin_amdgcn_mfma_f32_16x16x32_bf16(pk.s8, v1, acc1, 0, 0, 0);
            acc2 = __builtin_amdgcn_mfma_f32_16x16x32_bf16(pk.s8, v2, acc2, 0, 0, 0);
            acc3 = __builtin_amdgcn_mfma_f32_16x16x32_bf16(pk.s8, v3, acc3, 0, 0, 0);
            asum = __builtin_amdgcn_mfma_f32_16x16x32_bf16(pk.s8, ONES, asum, 0, 0, 0);
        }

        // 4. rotate scalars (renames under unroll 2) and issue step+2 loads
        bq_c = bq_n;
#pragma unroll
        for (int jtl = 0; jtl < 4; jtl++) { tAc[jtl] = tAn[jtl]; tBc[jtl] = tBn[jtl]; }
        bq_n = *(const uint4*)(bp + s2 * 4);
#pragma unroll
        for (int jtl = 0; jtl < 4; jtl++) {
            tAn[jtl] = *(const float4*)(tpp + (s2 * 4 + jtl) * 32);
            tBn[jtl] = *(const float4*)(tpp + (s2 * 4 + jtl) * 32 + 4);
        }
        __syncthreads();
    }

    // ---- normalize + store: lane (kq,col) has den(row kq*4+r) in asum[r] ----
    f32x4 accs[4] = {acc0, acc1, acc2, acc3};
#pragma unroll
    for (int r = 0; r < 4; r++) {
        const int row = i0 + w * 16 + kq * 4 + r;
        const float dv = asum[r];
        const float inv = (dv > 0.f) ? (1.f / dv) : 0.f;
        float* op = out + (size_t)row * HD + h * 64;
#pragma unroll
        for (int dt = 0; dt < 4; dt++)
            op[dt * 16 + col] = accs[dt][r] * inv;
    }
}

extern "C" void kernel_launch(void* const* d_in, const int* in_sizes, int n_in,
                              void* d_out, int out_size, void* d_ws, size_t ws_size,
                              hipStream_t stream) {
    const float* data = (const float*)d_in[0];   // (4096, 512)
    const float* conn = (const float*)d_in[1];   // (4096, 4096)
    const float* W    = (const float*)d_in[2];   // (512, 512)
    const float* bias = (const float*)d_in[3];   // (512,)
    const float* sp   = (const float*)d_in[4];   // (1, 8, 64)
    const float* tp   = (const float*)d_in[5];   // (1, 8, 64)
    float* out = (float*)d_out;                  // (4096, 512) fp32

    unsigned short* d1t = (unsigned short*)d_ws;              // 4 MB, fragment order
    unsigned short* Ab  = d1t + (size_t)HD * NN;              // 4 MB
    unsigned short* Wb  = Ab + (size_t)NN * IN_DIM;           // 512 KB
    float* srcT = (float*)(Wb + (size_t)HD * IN_DIM);         // 128 KB
    float* trgT = srcT + NH * NN;                             // 128 KB
    unsigned long long* bm = (unsigned long long*)(trgT + NH * NN); // 2 MB
    // total ~10.75 MB

    const int n4A = NN * IN_DIM / 4;   // 524288
    const int n4B = HD * IN_DIM / 4;   // 65536
    k_cast_scan<<<dim3(CAST_WGS + SCAN_WGS), 256, 0, stream>>>(data, Ab, n4A, W, Wb, n4B,
                                                               conn, bm);
    k_gemm_fused<<<dim3(NH, NN / 64), 512, 0, stream>>>(Ab, Wb, bias, sp, tp,
                                                        d1t, srcT, trgT);
    k_flash<<<dim3(NN / 128, NH), 512, 0, stream>>>((const unsigned*)bm, srcT, trgT, d1t, out);
}